// Round 1
// baseline (465.936 us; speedup 1.0000x reference)
//
#include <hip/hip_runtime.h>
#include <hip/hip_bf16.h>
#include <cstddef>

#define HH   256   // HEADS*HID
#define OUTC 64
#define NEG  0.2f

// ---------------- CSR build ----------------

__global__ __launch_bounds__(256) void hist_kernel(const int* __restrict__ ei, int E, int N,
                                                   int* __restrict__ deg) {
    int i = blockIdx.x * blockDim.x + threadIdx.x;
    int tot = E + N;
    if (i >= tot) return;
    int dst = (i < E) ? ei[E + i] : (i - E);   // self-loop for i>=E
    atomicAdd(&deg[dst], 1);
}

__global__ __launch_bounds__(1024) void scan_kernel(const int* __restrict__ deg,
                                                    int* __restrict__ offs, int n) {
    __shared__ int sh[1024];
    int t = threadIdx.x;
    int running = 0;
    for (int base = 0; base < n; base += 1024) {
        int i = base + t;
        int v = (i < n) ? deg[i] : 0;
        sh[t] = v;
        __syncthreads();
        for (int off = 1; off < 1024; off <<= 1) {
            int x = (t >= off) ? sh[t - off] : 0;
            __syncthreads();
            sh[t] += x;
            __syncthreads();
        }
        if (i < n) offs[i + 1] = running + sh[t];
        running += sh[1023];
        __syncthreads();
    }
    if (t == 0) offs[0] = 0;
}

__global__ __launch_bounds__(256) void scatter_kernel(const int* __restrict__ ei, int E, int N,
                                                      int* __restrict__ cursor,
                                                      int* __restrict__ esrc) {
    int i = blockIdx.x * blockDim.x + threadIdx.x;
    int tot = E + N;
    if (i >= tot) return;
    int src, dst;
    if (i < E) { src = ei[i]; dst = ei[E + i]; }
    else       { src = dst = i - E; }
    int pos = atomicAdd(&cursor[dst], 1);
    esrc[pos] = src;
}

// ---------------- fp32 tiled GEMM: C[M,N] = A[M,K] @ B[K,N] ----------------

template <bool RELU>
__global__ __launch_bounds__(256) void gemm_kernel(const float* __restrict__ A,
                                                   const float* __restrict__ B,
                                                   float* __restrict__ C,
                                                   int M, int N, int K) {
    __shared__ float As[16][64];
    __shared__ float Bs[16][64];
    int t = threadIdx.x;
    int tx = t & 15, ty = t >> 4;
    int row0 = blockIdx.x * 64, col0 = blockIdx.y * 64;
    float acc[4][4] = {};
    int arow = t >> 2, ak = (t & 3) << 2;
    int brow = t >> 4, bc = (t & 15) << 2;
    for (int kb = 0; kb < K; kb += 16) {
        float4 av = make_float4(0.f, 0.f, 0.f, 0.f);
        int gr = row0 + arow;
        if (gr < M) av = *(const float4*)(A + (size_t)gr * K + kb + ak);
        if (RELU) {
            av.x = fmaxf(av.x, 0.f); av.y = fmaxf(av.y, 0.f);
            av.z = fmaxf(av.z, 0.f); av.w = fmaxf(av.w, 0.f);
        }
        As[ak + 0][arow] = av.x;
        As[ak + 1][arow] = av.y;
        As[ak + 2][arow] = av.z;
        As[ak + 3][arow] = av.w;
        *(float4*)(&Bs[brow][bc]) = *(const float4*)(B + (size_t)(kb + brow) * N + col0 + bc);
        __syncthreads();
#pragma unroll
        for (int k = 0; k < 16; ++k) {
            float4 a = *(const float4*)(&As[k][ty * 4]);
            float4 b = *(const float4*)(&Bs[k][tx * 4]);
            float ar[4] = {a.x, a.y, a.z, a.w};
            float br[4] = {b.x, b.y, b.z, b.w};
#pragma unroll
            for (int i = 0; i < 4; ++i)
#pragma unroll
                for (int j = 0; j < 4; ++j)
                    acc[i][j] += ar[i] * br[j];
        }
        __syncthreads();
    }
#pragma unroll
    for (int i = 0; i < 4; ++i) {
        int gr = row0 + ty * 4 + i;
        if (gr < M) {
            float4 o = make_float4(acc[i][0], acc[i][1], acc[i][2], acc[i][3]);
            *(float4*)(C + (size_t)gr * N + col0 + tx * 4) = o;
        }
    }
}

// ---------------- attention score precompute ----------------

// layer1: h[N,256] viewed as [N,8,32]; a_s[n,h] = sum_c h[n,h,c]*att_s[h,c]
__global__ __launch_bounds__(64) void att1_kernel(const float* __restrict__ h,
                                                  const float* __restrict__ atts,
                                                  const float* __restrict__ attd,
                                                  float* __restrict__ as_,
                                                  float* __restrict__ ad_) {
    int n = blockIdx.x, lane = threadIdx.x;
    float4 hv = *(const float4*)(h + (size_t)n * HH + lane * 4);
    float4 sv = *(const float4*)(atts + lane * 4);
    float4 dv = *(const float4*)(attd + lane * 4);
    float s = hv.x * sv.x + hv.y * sv.y + hv.z * sv.z + hv.w * sv.w;
    float d = hv.x * dv.x + hv.y * dv.y + hv.z * dv.z + hv.w * dv.w;
    s += __shfl_xor(s, 1); s += __shfl_xor(s, 2); s += __shfl_xor(s, 4);
    d += __shfl_xor(d, 1); d += __shfl_xor(d, 2); d += __shfl_xor(d, 4);
    if ((lane & 7) == 0) {
        as_[n * 8 + (lane >> 3)] = s;
        ad_[n * 8 + (lane >> 3)] = d;
    }
}

// layer2: single head, 64 channels
__global__ __launch_bounds__(64) void att2_kernel(const float* __restrict__ h,
                                                  const float* __restrict__ atts,
                                                  const float* __restrict__ attd,
                                                  float* __restrict__ as_,
                                                  float* __restrict__ ad_) {
    int n = blockIdx.x, lane = threadIdx.x;
    float v = h[(size_t)n * OUTC + lane];
    float s = v * atts[lane];
    float d = v * attd[lane];
#pragma unroll
    for (int o = 1; o < 64; o <<= 1) { s += __shfl_xor(s, o); d += __shfl_xor(d, o); }
    if (lane == 0) { as_[n] = s; ad_[n] = d; }
}

// ---------------- layer-1 aggregation (8 heads x 32 ch), one wave per dst ----------------

__global__ __launch_bounds__(64) void agg1_kernel(const int* __restrict__ offs,
                                                  const int* __restrict__ esrc,
                                                  const float* __restrict__ as_,
                                                  const float* __restrict__ ad_,
                                                  const float* __restrict__ h,
                                                  const float* __restrict__ bias,
                                                  float* __restrict__ out) {
    int n = blockIdx.x;
    int lane = threadIdx.x;
    int beg = offs[n], end = offs[n + 1];
    int deg = end - beg;
    int hA = lane & 7;      // head for score work
    int j  = lane >> 3;     // edge slot within chunk of 8
    int hB = lane >> 3;     // head owning this lane's 4 channels
    float adh = ad_[n * 8 + hA];

    // pass 1: per-head max
    float mx = -1e30f;
    for (int i = j; i < deg; i += 8) {
        int s = esrc[beg + i];
        float e = as_[s * 8 + hA] + adh;
        e = (e > 0.f) ? e : NEG * e;
        mx = fmaxf(mx, e);
    }
    mx = fmaxf(mx, __shfl_xor(mx, 8));
    mx = fmaxf(mx, __shfl_xor(mx, 16));
    mx = fmaxf(mx, __shfl_xor(mx, 32));

    // pass 2: fused exp + weighted accumulate, in chunks of 8 edges
    __shared__ float ex_sh[64];
    __shared__ int   src_sh[8];
    float4 acc = make_float4(0.f, 0.f, 0.f, 0.f);
    float dsum = 0.f;
    for (int cs = 0; cs < deg; cs += 8) {
        int i = cs + j;
        float ex = 0.f;
        int s = 0;
        if (i < deg) {
            s = esrc[beg + i];
            float e = as_[s * 8 + hA] + adh;
            e = (e > 0.f) ? e : NEG * e;
            ex = __expf(e - mx);
        }
        ex_sh[lane] = ex;               // == ex_sh[j*8 + hA]
        if (hA == 0) src_sh[j] = s;
        dsum += ex;
        __syncthreads();
        int lim = min(8, deg - cs);
        for (int jj = 0; jj < lim; ++jj) {
            int s2 = src_sh[jj];
            float w = ex_sh[jj * 8 + hB];
            float4 hv = *(const float4*)(h + (size_t)s2 * HH + lane * 4);
            acc.x += w * hv.x; acc.y += w * hv.y;
            acc.z += w * hv.z; acc.w += w * hv.w;
        }
        __syncthreads();
    }
    dsum += __shfl_xor(dsum, 8);
    dsum += __shfl_xor(dsum, 16);
    dsum += __shfl_xor(dsum, 32);
    float denom = __shfl(dsum, hB);     // lane hB holds head hB's sum
    float inv = 1.f / (denom + 1e-16f);
    int c0 = lane * 4;
    float4 o;
    o.x = acc.x * inv + bias[c0 + 0];
    o.y = acc.y * inv + bias[c0 + 1];
    o.z = acc.z * inv + bias[c0 + 2];
    o.w = acc.w * inv + bias[c0 + 3];
    *(float4*)(out + (size_t)n * HH + c0) = o;
}

// ---------------- layer-2 aggregation (1 head x 64 ch), one wave per dst ----------------

__global__ __launch_bounds__(64) void agg2_kernel(const int* __restrict__ offs,
                                                  const int* __restrict__ esrc,
                                                  const float* __restrict__ as_,
                                                  const float* __restrict__ ad_,
                                                  const float* __restrict__ h,
                                                  const float* __restrict__ bias,
                                                  float* __restrict__ out) {
    int n = blockIdx.x;
    int lane = threadIdx.x;
    int beg = offs[n], end = offs[n + 1];
    int deg = end - beg;
    float adn = ad_[n];

    float mx = -1e30f;
    for (int i = lane; i < deg; i += 64) {
        float e = as_[esrc[beg + i]] + adn;
        e = (e > 0.f) ? e : NEG * e;
        mx = fmaxf(mx, e);
    }
#pragma unroll
    for (int o = 1; o < 64; o <<= 1) mx = fmaxf(mx, __shfl_xor(mx, o));

    __shared__ float ex_sh[64];
    __shared__ int   src_sh[64];
    float acc = 0.f, dsum = 0.f;
    for (int cs = 0; cs < deg; cs += 64) {
        int i = cs + lane;
        float ex = 0.f;
        int s = 0;
        if (i < deg) {
            s = esrc[beg + i];
            float e = as_[s] + adn;
            e = (e > 0.f) ? e : NEG * e;
            ex = __expf(e - mx);
        }
        ex_sh[lane] = ex;
        src_sh[lane] = s;
        dsum += ex;
        __syncthreads();
        int lim = min(64, deg - cs);
        for (int jj = 0; jj < lim; ++jj)
            acc += ex_sh[jj] * h[(size_t)src_sh[jj] * OUTC + lane];
        __syncthreads();
    }
#pragma unroll
    for (int o = 1; o < 64; o <<= 1) dsum += __shfl_xor(dsum, o);
    out[(size_t)n * OUTC + lane] = acc / (dsum + 1e-16f) + bias[lane];
}

// ---------------- launcher ----------------

extern "C" void kernel_launch(void* const* d_in, const int* in_sizes, int n_in,
                              void* d_out, int out_size, void* d_ws, size_t ws_size,
                              hipStream_t stream) {
    const float* x    = (const float*)d_in[0];
    const int*   ei   = (const int*)d_in[1];
    const float* W1   = (const float*)d_in[2];
    const float* as1w = (const float*)d_in[3];
    const float* ad1w = (const float*)d_in[4];
    const float* b1   = (const float*)d_in[5];
    const float* W2   = (const float*)d_in[6];
    const float* as2w = (const float*)d_in[7];
    const float* ad2w = (const float*)d_in[8];
    const float* b2   = (const float*)d_in[9];
    float* out = (float*)d_out;

    int N = in_sizes[0] / 128;
    int E = in_sizes[1] / 2;
    int Etot = E + N;

    float* ws = (float*)d_ws;
    float* h1   = ws;  ws += (size_t)N * HH;
    float* o1   = ws;  ws += (size_t)N * HH;
    float* h2   = ws;  ws += (size_t)N * OUTC;
    float* a_s1 = ws;  ws += (size_t)N * 8;
    float* a_d1 = ws;  ws += (size_t)N * 8;
    float* a_s2 = ws;  ws += N;
    float* a_d2 = ws;  ws += N;
    int* deg    = (int*)ws;  ws += N;
    int* offs   = (int*)ws;  ws += (N + 1);
    int* cursor = (int*)ws;  ws += N;
    int* esrc   = (int*)ws;

    // CSR by destination (includes self-loops)
    hipMemsetAsync(deg, 0, sizeof(int) * N, stream);
    hist_kernel<<<(Etot + 255) / 256, 256, 0, stream>>>(ei, E, N, deg);
    scan_kernel<<<1, 1024, 0, stream>>>(deg, offs, N);
    hipMemcpyAsync(cursor, offs, sizeof(int) * N, hipMemcpyDeviceToDevice, stream);
    scatter_kernel<<<(Etot + 255) / 256, 256, 0, stream>>>(ei, E, N, cursor, esrc);

    // layer 1
    gemm_kernel<false><<<dim3((N + 63) / 64, HH / 64), 256, 0, stream>>>(x, W1, h1, N, HH, 128);
    att1_kernel<<<N, 64, 0, stream>>>(h1, as1w, ad1w, a_s1, a_d1);
    agg1_kernel<<<N, 64, 0, stream>>>(offs, esrc, a_s1, a_d1, h1, b1, o1);

    // layer 2 (ReLU fused into GEMM2 A-load)
    gemm_kernel<true><<<dim3((N + 63) / 64, OUTC / 64), 256, 0, stream>>>(o1, W2, h2, N, OUTC, HH);
    att2_kernel<<<N, 64, 0, stream>>>(h2, as2w, ad2w, a_s2, a_d2);
    agg2_kernel<<<N, 64, 0, stream>>>(offs, esrc, a_s2, a_d2, h2, b2, out);
}

// Round 2
// 335.937 us; speedup vs baseline: 1.3870x; 1.3870x over previous
//
#include <hip/hip_runtime.h>
#include <hip/hip_fp16.h>
#include <cstddef>

#define HH   256   // HEADS*HID
#define OUTC 64
#define NEG  0.2f

// ---------------- CSR build ----------------

__global__ __launch_bounds__(256) void hist_kernel(const int* __restrict__ ei, int E, int N,
                                                   int* __restrict__ deg) {
    int i = blockIdx.x * blockDim.x + threadIdx.x;
    int tot = E + N;
    if (i >= tot) return;
    int dst = (i < E) ? ei[E + i] : (i - E);   // self-loop for i>=E
    atomicAdd(&deg[dst], 1);
}

// multi-block scan: block-local inclusive scan + block partial
__global__ __launch_bounds__(256) void scan_block(const int* __restrict__ deg,
                                                  int* __restrict__ offs,
                                                  int* __restrict__ part, int n) {
    __shared__ int sh[256];
    int t = threadIdx.x;
    int i = blockIdx.x * 256 + t;
    int v = (i < n) ? deg[i] : 0;
    sh[t] = v;
    __syncthreads();
    for (int off = 1; off < 256; off <<= 1) {
        int x = (t >= off) ? sh[t - off] : 0;
        __syncthreads();
        sh[t] += x;
        __syncthreads();
    }
    if (i < n) offs[i + 1] = sh[t];
    if (t == 255) part[blockIdx.x] = sh[255];
}

__global__ __launch_bounds__(256) void scan_part(int* __restrict__ part, int nb) {
    __shared__ int sh[256];
    int t = threadIdx.x;
    int v = (t < nb) ? part[t] : 0;
    sh[t] = v;
    __syncthreads();
    for (int off = 1; off < 256; off <<= 1) {
        int x = (t >= off) ? sh[t - off] : 0;
        __syncthreads();
        sh[t] += x;
        __syncthreads();
    }
    int excl = (t == 0) ? 0 : sh[t - 1];
    __syncthreads();
    if (t < nb) part[t] = excl;
}

__global__ __launch_bounds__(256) void scan_add(int* __restrict__ offs,
                                                const int* __restrict__ part, int n) {
    int i = blockIdx.x * 256 + threadIdx.x;
    if (i < n) offs[i + 1] += part[blockIdx.x];
    if (i == 0) offs[0] = 0;
}

__global__ __launch_bounds__(256) void scatter_kernel(const int* __restrict__ ei, int E, int N,
                                                      int* __restrict__ cursor,
                                                      int* __restrict__ esrc) {
    int i = blockIdx.x * blockDim.x + threadIdx.x;
    int tot = E + N;
    if (i >= tot) return;
    int src, dst;
    if (i < E) { src = ei[i]; dst = ei[E + i]; }
    else       { src = dst = i - E; }
    int pos = atomicAdd(&cursor[dst], 1);
    esrc[pos] = src;
}

// ---------------- fp32 tiled GEMM: C[M,N] = A[M,K] @ B[K,N] ----------------
// HALF_OUT: store C as fp16 (packed uint2 per 4 channels)

template <bool RELU, bool HALF_OUT>
__global__ __launch_bounds__(256) void gemm_kernel(const float* __restrict__ A,
                                                   const float* __restrict__ B,
                                                   void* __restrict__ Cv,
                                                   int M, int N, int K) {
    __shared__ float As[16][64];
    __shared__ float Bs[16][64];
    int t = threadIdx.x;
    int tx = t & 15, ty = t >> 4;
    int row0 = blockIdx.x * 64, col0 = blockIdx.y * 64;
    float acc[4][4] = {};
    int arow = t >> 2, ak = (t & 3) << 2;
    int brow = t >> 4, bc = (t & 15) << 2;
    for (int kb = 0; kb < K; kb += 16) {
        float4 av = make_float4(0.f, 0.f, 0.f, 0.f);
        int gr = row0 + arow;
        if (gr < M) av = *(const float4*)(A + (size_t)gr * K + kb + ak);
        if (RELU) {
            av.x = fmaxf(av.x, 0.f); av.y = fmaxf(av.y, 0.f);
            av.z = fmaxf(av.z, 0.f); av.w = fmaxf(av.w, 0.f);
        }
        As[ak + 0][arow] = av.x;
        As[ak + 1][arow] = av.y;
        As[ak + 2][arow] = av.z;
        As[ak + 3][arow] = av.w;
        *(float4*)(&Bs[brow][bc]) = *(const float4*)(B + (size_t)(kb + brow) * N + col0 + bc);
        __syncthreads();
#pragma unroll
        for (int k = 0; k < 16; ++k) {
            float4 a = *(const float4*)(&As[k][ty * 4]);
            float4 b = *(const float4*)(&Bs[k][tx * 4]);
            float ar[4] = {a.x, a.y, a.z, a.w};
            float br[4] = {b.x, b.y, b.z, b.w};
#pragma unroll
            for (int i = 0; i < 4; ++i)
#pragma unroll
                for (int j = 0; j < 4; ++j)
                    acc[i][j] += ar[i] * br[j];
        }
        __syncthreads();
    }
#pragma unroll
    for (int i = 0; i < 4; ++i) {
        int gr = row0 + ty * 4 + i;
        if (gr < M) {
            if (HALF_OUT) {
                __half* C = (__half*)Cv;
                union { __half2 h[2]; uint2 u; } pk;
                pk.h[0] = __floats2half2_rn(acc[i][0], acc[i][1]);
                pk.h[1] = __floats2half2_rn(acc[i][2], acc[i][3]);
                *(uint2*)(C + (size_t)gr * N + col0 + tx * 4) = pk.u;
            } else {
                float* C = (float*)Cv;
                float4 o = make_float4(acc[i][0], acc[i][1], acc[i][2], acc[i][3]);
                *(float4*)(C + (size_t)gr * N + col0 + tx * 4) = o;
            }
        }
    }
}

// ---------------- attention score precompute ----------------

// layer1: h[N,256] fp16 viewed as [N,8,32]; a_s[n,h] = sum_c h[n,h,c]*att_s[h,c]
__global__ __launch_bounds__(64) void att1_kernel(const __half* __restrict__ h,
                                                  const float* __restrict__ atts,
                                                  const float* __restrict__ attd,
                                                  float* __restrict__ as_,
                                                  float* __restrict__ ad_) {
    int n = blockIdx.x, lane = threadIdx.x;
    uint2 hv = *(const uint2*)(h + (size_t)n * HH + lane * 4);
    float2 f01 = __half22float2(*(const __half2*)&hv.x);
    float2 f23 = __half22float2(*(const __half2*)&hv.y);
    float4 sv = *(const float4*)(atts + lane * 4);
    float4 dv = *(const float4*)(attd + lane * 4);
    float s = f01.x * sv.x + f01.y * sv.y + f23.x * sv.z + f23.y * sv.w;
    float d = f01.x * dv.x + f01.y * dv.y + f23.x * dv.z + f23.y * dv.w;
    s += __shfl_xor(s, 1); s += __shfl_xor(s, 2); s += __shfl_xor(s, 4);
    d += __shfl_xor(d, 1); d += __shfl_xor(d, 2); d += __shfl_xor(d, 4);
    if ((lane & 7) == 0) {
        as_[n * 8 + (lane >> 3)] = s;
        ad_[n * 8 + (lane >> 3)] = d;
    }
}

// layer2: single head, 64 channels, h fp16
__global__ __launch_bounds__(64) void att2_kernel(const __half* __restrict__ h,
                                                  const float* __restrict__ atts,
                                                  const float* __restrict__ attd,
                                                  float* __restrict__ as_,
                                                  float* __restrict__ ad_) {
    int n = blockIdx.x, lane = threadIdx.x;
    float v = __half2float(h[(size_t)n * OUTC + lane]);
    float s = v * atts[lane];
    float d = v * attd[lane];
#pragma unroll
    for (int o = 1; o < 64; o <<= 1) { s += __shfl_xor(s, o); d += __shfl_xor(d, o); }
    if (lane == 0) { as_[n] = s; ad_[n] = d; }
}

// ---------------- layer-1 aggregation, single pass (no max shift: |e|<~4) ----------------

__global__ __launch_bounds__(64) void agg1_kernel(const int* __restrict__ offs,
                                                  const int* __restrict__ esrc,
                                                  const float* __restrict__ as_,
                                                  const float* __restrict__ ad_,
                                                  const __half* __restrict__ h,
                                                  const float* __restrict__ bias,
                                                  float* __restrict__ out) {
    int n = blockIdx.x;
    int lane = threadIdx.x;
    int beg = offs[n], end = offs[n + 1];
    int deg = end - beg;
    int hA = lane & 7;      // head for score work
    int j  = lane >> 3;     // edge slot within chunk of 8
    int hB = lane >> 3;     // head owning this lane's 4 channels
    float adh = ad_[n * 8 + hA];

    float4 acc = make_float4(0.f, 0.f, 0.f, 0.f);
    float dsum = 0.f;
    for (int cs = 0; cs < deg; cs += 8) {
        int i = cs + j;
        float ex = 0.f;
        int s = 0;
        if (i < deg) {
            s = esrc[beg + i];
            float e = as_[s * 8 + hA] + adh;
            e = (e > 0.f) ? e : NEG * e;
            ex = __expf(e);
        }
        dsum += ex;
        if (cs + 8 <= deg) {
#pragma unroll
            for (int jj = 0; jj < 8; ++jj) {
                int s2 = __shfl(s, jj * 8);
                float w = __shfl(ex, jj * 8 + hB);
                uint2 hv = *(const uint2*)(h + (size_t)s2 * HH + lane * 4);
                float2 f01 = __half22float2(*(const __half2*)&hv.x);
                float2 f23 = __half22float2(*(const __half2*)&hv.y);
                acc.x += w * f01.x; acc.y += w * f01.y;
                acc.z += w * f23.x; acc.w += w * f23.y;
            }
        } else {
            int lim = deg - cs;
            for (int jj = 0; jj < lim; ++jj) {
                int s2 = __shfl(s, jj * 8);
                float w = __shfl(ex, jj * 8 + hB);
                uint2 hv = *(const uint2*)(h + (size_t)s2 * HH + lane * 4);
                float2 f01 = __half22float2(*(const __half2*)&hv.x);
                float2 f23 = __half22float2(*(const __half2*)&hv.y);
                acc.x += w * f01.x; acc.y += w * f01.y;
                acc.z += w * f23.x; acc.w += w * f23.y;
            }
        }
    }
    dsum += __shfl_xor(dsum, 8);
    dsum += __shfl_xor(dsum, 16);
    dsum += __shfl_xor(dsum, 32);
    float denom = __shfl(dsum, hB);     // lane hB holds head hB's sum
    float inv = 1.f / (denom + 1e-16f);
    int c0 = lane * 4;
    float4 o;
    o.x = acc.x * inv + bias[c0 + 0];
    o.y = acc.y * inv + bias[c0 + 1];
    o.z = acc.z * inv + bias[c0 + 2];
    o.w = acc.w * inv + bias[c0 + 3];
    *(float4*)(out + (size_t)n * HH + c0) = o;
}

// ---------------- layer-2 aggregation (1 head x 64 ch), single pass ----------------

__global__ __launch_bounds__(64) void agg2_kernel(const int* __restrict__ offs,
                                                  const int* __restrict__ esrc,
                                                  const float* __restrict__ as_,
                                                  const float* __restrict__ ad_,
                                                  const __half* __restrict__ h,
                                                  const float* __restrict__ bias,
                                                  float* __restrict__ out) {
    int n = blockIdx.x;
    int lane = threadIdx.x;
    int beg = offs[n], end = offs[n + 1];
    int deg = end - beg;
    float adn = ad_[n];

    float acc = 0.f, dsum = 0.f;
    for (int cs = 0; cs < deg; cs += 64) {
        int i = cs + lane;
        float ex = 0.f;
        int s = 0;
        if (i < deg) {
            s = esrc[beg + i];
            float e = as_[s] + adn;
            e = (e > 0.f) ? e : NEG * e;
            ex = __expf(e);
        }
        dsum += ex;
        int lim = min(64, deg - cs);
        for (int jj = 0; jj < lim; ++jj) {
            int s2 = __shfl(s, jj);
            float w = __shfl(ex, jj);
            acc += w * __half2float(h[(size_t)s2 * OUTC + lane]);
        }
    }
#pragma unroll
    for (int o = 1; o < 64; o <<= 1) dsum += __shfl_xor(dsum, o);
    out[(size_t)n * OUTC + lane] = acc / (dsum + 1e-16f) + bias[lane];
}

// ---------------- launcher ----------------

extern "C" void kernel_launch(void* const* d_in, const int* in_sizes, int n_in,
                              void* d_out, int out_size, void* d_ws, size_t ws_size,
                              hipStream_t stream) {
    const float* x    = (const float*)d_in[0];
    const int*   ei   = (const int*)d_in[1];
    const float* W1   = (const float*)d_in[2];
    const float* as1w = (const float*)d_in[3];
    const float* ad1w = (const float*)d_in[4];
    const float* b1   = (const float*)d_in[5];
    const float* W2   = (const float*)d_in[6];
    const float* as2w = (const float*)d_in[7];
    const float* ad2w = (const float*)d_in[8];
    const float* b2   = (const float*)d_in[9];
    float* out = (float*)d_out;

    int N = in_sizes[0] / 128;
    int E = in_sizes[1] / 2;
    int Etot = E + N;
    int nb = (N + 255) / 256;

    char* p = (char*)d_ws;
    auto alloc = [&](size_t bytes) { char* r = p; p += (bytes + 255) & ~(size_t)255; return r; };
    __half* h1  = (__half*)alloc((size_t)N * HH * 2);
    float*  o1  = (float*) alloc((size_t)N * HH * 4);
    __half* h2  = (__half*)alloc((size_t)N * OUTC * 2);
    float* a_s1 = (float*) alloc((size_t)N * 8 * 4);
    float* a_d1 = (float*) alloc((size_t)N * 8 * 4);
    float* a_s2 = (float*) alloc((size_t)N * 4);
    float* a_d2 = (float*) alloc((size_t)N * 4);
    int* deg    = (int*)   alloc((size_t)N * 4);
    int* offs   = (int*)   alloc((size_t)(N + 1) * 4);
    int* cursor = (int*)   alloc((size_t)N * 4);
    int* part   = (int*)   alloc((size_t)nb * 4);
    int* esrc   = (int*)   alloc((size_t)Etot * 4);

    // CSR by destination (includes self-loops)
    hipMemsetAsync(deg, 0, sizeof(int) * N, stream);
    hist_kernel<<<(Etot + 255) / 256, 256, 0, stream>>>(ei, E, N, deg);
    scan_block<<<nb, 256, 0, stream>>>(deg, offs, part, N);
    scan_part<<<1, 256, 0, stream>>>(part, nb);
    scan_add<<<nb, 256, 0, stream>>>(offs, part, N);
    hipMemcpyAsync(cursor, offs, sizeof(int) * N, hipMemcpyDeviceToDevice, stream);
    scatter_kernel<<<(Etot + 255) / 256, 256, 0, stream>>>(ei, E, N, cursor, esrc);

    // layer 1 (h1 stored fp16 for the gather)
    gemm_kernel<false, true><<<dim3((N + 63) / 64, HH / 64), 256, 0, stream>>>(x, W1, h1, N, HH, 128);
    att1_kernel<<<N, 64, 0, stream>>>(h1, as1w, ad1w, a_s1, a_d1);
    agg1_kernel<<<N, 64, 0, stream>>>(offs, esrc, a_s1, a_d1, h1, b1, o1);

    // layer 2 (ReLU fused into GEMM2 A-load; h2 stored fp16)
    gemm_kernel<true, true><<<dim3((N + 63) / 64, OUTC / 64), 256, 0, stream>>>(o1, W2, h2, N, OUTC, HH);
    att2_kernel<<<N, 64, 0, stream>>>(h2, as2w, ad2w, a_s2, a_d2);
    agg2_kernel<<<N, 64, 0, stream>>>(offs, esrc, a_s2, a_d2, h2, b2, out);
}

// Round 5
// 290.041 us; speedup vs baseline: 1.6065x; 1.1582x over previous
//
#include <hip/hip_runtime.h>
#include <cstddef>

#define HH   256   // HEADS*HID
#define OUTC 64
#define NEG  0.2f

typedef _Float16 half8  __attribute__((ext_vector_type(8)));
typedef _Float16 half4v __attribute__((ext_vector_type(4)));
typedef float    f32x4  __attribute__((ext_vector_type(4)));

// ---------------- CSR build ----------------

__global__ __launch_bounds__(256) void hist_kernel(const int* __restrict__ ei, int E, int N,
                                                   int* __restrict__ deg) {
    int i = blockIdx.x * blockDim.x + threadIdx.x;
    int tot = E + N;
    if (i >= tot) return;
    int dst = (i < E) ? ei[E + i] : (i - E);   // self-loop for i>=E
    atomicAdd(&deg[dst], 1);
}

__global__ __launch_bounds__(256) void scan_block(const int* __restrict__ deg,
                                                  int* __restrict__ offs,
                                                  int* __restrict__ part, int n) {
    __shared__ int sh[256];
    int t = threadIdx.x;
    int i = blockIdx.x * 256 + t;
    int v = (i < n) ? deg[i] : 0;
    sh[t] = v;
    __syncthreads();
    for (int off = 1; off < 256; off <<= 1) {
        int x = (t >= off) ? sh[t - off] : 0;
        __syncthreads();
        sh[t] += x;
        __syncthreads();
    }
    if (i < n) offs[i + 1] = sh[t];
    if (t == 255) part[blockIdx.x] = sh[255];
}

__global__ __launch_bounds__(256) void scan_part(int* __restrict__ part, int nb) {
    __shared__ int sh[256];
    int t = threadIdx.x;
    int v = (t < nb) ? part[t] : 0;
    sh[t] = v;
    __syncthreads();
    for (int off = 1; off < 256; off <<= 1) {
        int x = (t >= off) ? sh[t - off] : 0;
        __syncthreads();
        sh[t] += x;
        __syncthreads();
    }
    int excl = (t == 0) ? 0 : sh[t - 1];
    __syncthreads();
    if (t < nb) part[t] = excl;
}

__global__ __launch_bounds__(256) void scan_add(int* __restrict__ offs,
                                                const int* __restrict__ part, int n) {
    int i = blockIdx.x * 256 + threadIdx.x;
    if (i < n) offs[i + 1] += part[blockIdx.x];
    if (i == 0) offs[0] = 0;
}

__global__ __launch_bounds__(256) void scatter_kernel(const int* __restrict__ ei, int E, int N,
                                                      int* __restrict__ cursor,
                                                      int* __restrict__ esrc) {
    int i = blockIdx.x * blockDim.x + threadIdx.x;
    int tot = E + N;
    if (i >= tot) return;
    int src, dst;
    if (i < E) { src = ei[i]; dst = ei[E + i]; }
    else       { src = dst = i - E; }
    int pos = atomicAdd(&cursor[dst], 1);
    esrc[pos] = src;
}

// ---------------- weight transpose + cast: Wt[n][k] = (half)W[k][n] ----------------

__global__ __launch_bounds__(256) void cast_wt(const float* __restrict__ W,
                                               _Float16* __restrict__ Wt, int K, int N) {
    int i = blockIdx.x * 256 + threadIdx.x;
    if (i >= K * N) return;
    int n = i / K, k = i - n * K;
    Wt[i] = (_Float16)W[(size_t)k * N + n];
}

// ---------------- MFMA fp16 GEMM, full-N per block ----------------
// C[M,N] = A[M,K] @ B[K,N], B given as Bt[N][K]. C stored fp16.

template <int K, int NT, bool AF32>
__global__ __launch_bounds__(256) void mfma_gemm(const void* __restrict__ Av,
                                                 const _Float16* __restrict__ Bt,
                                                 _Float16* __restrict__ C,
                                                 int M) {
    constexpr int N = NT * 16;
    int t = threadIdx.x;
    int w = t >> 6, l = t & 63;
    int lm = l & 15, lk = l >> 4;
    int row0 = blockIdx.x * 64 + w * 16;
    int rA = row0 + lm; if (rA >= M) rA = M - 1;
    int kOff = lk * 8;

    f32x4 acc[NT];
#pragma unroll
    for (int i = 0; i < NT; ++i) acc[i] = (f32x4){0.f, 0.f, 0.f, 0.f};

    const float*    Af = (const float*)Av    + (size_t)rA * K + kOff;
    const _Float16* Ah = (const _Float16*)Av + (size_t)rA * K + kOff;
    const _Float16* Bp = Bt + (size_t)lm * K + kOff;

#pragma unroll 1
    for (int ks = 0; ks < K / 32; ++ks) {
        half8 a;
        if constexpr (AF32) {
            float4 a0 = *(const float4*)(Af + ks * 32);
            float4 a1 = *(const float4*)(Af + ks * 32 + 4);
            a = (half8){(_Float16)a0.x, (_Float16)a0.y, (_Float16)a0.z, (_Float16)a0.w,
                        (_Float16)a1.x, (_Float16)a1.y, (_Float16)a1.z, (_Float16)a1.w};
        } else {
            a = *(const half8*)(Ah + ks * 32);
        }
#pragma unroll
        for (int nt = 0; nt < NT; ++nt) {
            half8 b = *(const half8*)(Bp + (size_t)nt * 16 * K + ks * 32);
            acc[nt] = __builtin_amdgcn_mfma_f32_16x16x32_f16(a, b, acc[nt], 0, 0, 0);
        }
    }

    // store C fp16: row = rBase + r, col = nt*16 + lm
    int rBase = row0 + lk * 4;
#pragma unroll
    for (int nt = 0; nt < NT; ++nt) {
        int col = nt * 16 + lm;
#pragma unroll
        for (int r = 0; r < 4; ++r) {
            int row = rBase + r;
            if (row < M) C[(size_t)row * N + col] = (_Float16)acc[nt][r];
        }
    }
}

// ---------------- attention score precompute ----------------

// layer1: h[N,256] fp16 viewed as [N,8,32]; a_s[n,h] = sum_c h[n,h,c]*att_s[h,c]
__global__ __launch_bounds__(64) void att1_kernel(const _Float16* __restrict__ h,
                                                  const float* __restrict__ atts,
                                                  const float* __restrict__ attd,
                                                  float* __restrict__ as_,
                                                  float* __restrict__ ad_) {
    int n = blockIdx.x, lane = threadIdx.x;
    half4v hv = *(const half4v*)(h + (size_t)n * HH + lane * 4);
    float4 sv = *(const float4*)(atts + lane * 4);
    float4 dv = *(const float4*)(attd + lane * 4);
    float s = (float)hv[0] * sv.x + (float)hv[1] * sv.y + (float)hv[2] * sv.z + (float)hv[3] * sv.w;
    float d = (float)hv[0] * dv.x + (float)hv[1] * dv.y + (float)hv[2] * dv.z + (float)hv[3] * dv.w;
    s += __shfl_xor(s, 1); s += __shfl_xor(s, 2); s += __shfl_xor(s, 4);
    d += __shfl_xor(d, 1); d += __shfl_xor(d, 2); d += __shfl_xor(d, 4);
    if ((lane & 7) == 0) {
        as_[n * 8 + (lane >> 3)] = s;
        ad_[n * 8 + (lane >> 3)] = d;
    }
}

// layer2: single head, 64 channels, h fp16
__global__ __launch_bounds__(64) void att2_kernel(const _Float16* __restrict__ h,
                                                  const float* __restrict__ atts,
                                                  const float* __restrict__ attd,
                                                  float* __restrict__ as_,
                                                  float* __restrict__ ad_) {
    int n = blockIdx.x, lane = threadIdx.x;
    float v = (float)h[(size_t)n * OUTC + lane];
    float s = v * atts[lane];
    float d = v * attd[lane];
#pragma unroll
    for (int o = 1; o < 64; o <<= 1) { s += __shfl_xor(s, o); d += __shfl_xor(d, o); }
    if (lane == 0) { as_[n] = s; ad_[n] = d; }
}

// ---------------- layer-1 aggregation: 8 heads x 32ch, 16B/lane gathers ----------------
// writes o1h = fp16 ReLU(agg + bias)  (feeds GEMM2 directly)
// NOTE: all __shfl broadcasts run UNCONDITIONALLY with wave-uniform trip counts;
// only loads/accumulates are guarded. shfl from an exec-masked lane is undefined
// (this was the r3/r4 correctness bug).

__global__ __launch_bounds__(256) void agg1_kernel(const int* __restrict__ offs,
                                                   const int* __restrict__ esrc,
                                                   const float* __restrict__ as_,
                                                   const float* __restrict__ ad_,
                                                   const _Float16* __restrict__ h,
                                                   const float* __restrict__ bias,
                                                   _Float16* __restrict__ o1h) {
    int n = blockIdx.x * 4 + (threadIdx.x >> 6);
    int l = threadIdx.x & 63;
    int beg = offs[n], deg = offs[n + 1] - beg;
    int hA = l & 7, j = l >> 3;     // score phase: slot j, head hA
    int cg = l & 31;                // channel group: channels cg*8..+7
    int hB = cg >> 2;               // head owning those channels
    int rs = l >> 5;                // row parity (even/odd slots)
    float adh = ad_[n * 8 + hA];

    float acc[8] = {0.f, 0.f, 0.f, 0.f, 0.f, 0.f, 0.f, 0.f};
    float dsum = 0.f;
    for (int cs = 0; cs < deg; cs += 8) {
        int i = cs + j;
        float ex = 0.f; int s = 0;
        if (i < deg) {
            s = esrc[beg + i];
            float e = as_[s * 8 + hA] + adh;
            e = (e > 0.f) ? e : NEG * e;
            ex = __expf(e);
        }
        dsum += ex;
        int lim = deg - cs;
        if (lim >= 8) {
#pragma unroll
            for (int it = 0; it < 4; ++it) {
                int slot = it * 2 + rs;
                int s2 = __shfl(s, slot * 8);
                float wgt = __shfl(ex, slot * 8 + hB);
                half8 hv = *(const half8*)(h + (size_t)s2 * HH + cg * 8);
#pragma unroll
                for (int q = 0; q < 8; ++q) acc[q] += wgt * (float)hv[q];
            }
        } else {
            int itmax = (lim + 1) >> 1;             // wave-uniform
            for (int it = 0; it < itmax; ++it) {
                int slot = it * 2 + rs;
                int s2 = __shfl(s, slot * 8);       // all lanes execute
                float wgt = __shfl(ex, slot * 8 + hB);
                if (slot < lim) {
                    half8 hv = *(const half8*)(h + (size_t)s2 * HH + cg * 8);
#pragma unroll
                    for (int q = 0; q < 8; ++q) acc[q] += wgt * (float)hv[q];
                }
            }
        }
    }
#pragma unroll
    for (int q = 0; q < 8; ++q) acc[q] += __shfl_xor(acc[q], 32);
    dsum += __shfl_xor(dsum, 8); dsum += __shfl_xor(dsum, 16); dsum += __shfl_xor(dsum, 32);
    float denom = __shfl(dsum, hB);
    float inv = 1.f / (denom + 1e-16f);
    if (l < 32) {
        half8 o;
#pragma unroll
        for (int q = 0; q < 8; ++q) {
            float v = acc[q] * inv + bias[cg * 8 + q];
            o[q] = (_Float16)fmaxf(v, 0.f);     // bias + ReLU fused, fp16 out
        }
        *(half8*)(o1h + (size_t)n * HH + cg * 8) = o;
    }
}

// ---------------- layer-2 aggregation: 1 head x 64ch, 8B/lane gathers ----------------

__global__ __launch_bounds__(256) void agg2_kernel(const int* __restrict__ offs,
                                                   const int* __restrict__ esrc,
                                                   const float* __restrict__ as_,
                                                   const float* __restrict__ ad_,
                                                   const _Float16* __restrict__ h,
                                                   const float* __restrict__ bias,
                                                   float* __restrict__ out) {
    int n = blockIdx.x * 4 + (threadIdx.x >> 6);
    int l = threadIdx.x & 63;
    int beg = offs[n], deg = offs[n + 1] - beg;
    float adn = ad_[n];
    int cg = l & 15;                // channels cg*4..+3
    int rs = l >> 4;                // row slot 0..3

    float acc[4] = {0.f, 0.f, 0.f, 0.f};
    float dsum = 0.f;
    for (int cs = 0; cs < deg; cs += 64) {
        int i = cs + l;
        float ex = 0.f; int s = 0;
        if (i < deg) {
            s = esrc[beg + i];
            float e = as_[s] + adn;
            e = (e > 0.f) ? e : NEG * e;
            ex = __expf(e);
        }
        dsum += ex;
        int lim = deg - cs; if (lim > 64) lim = 64;
        int gmax = (lim + 3) >> 2;                  // wave-uniform
        for (int g = 0; g < gmax; ++g) {
            int slot = g * 4 + rs;
            int s2 = __shfl(s, slot);               // all lanes execute
            float wgt = __shfl(ex, slot);
            if (slot < lim) {
                half4v hv = *(const half4v*)(h + (size_t)s2 * OUTC + cg * 4);
#pragma unroll
                for (int q = 0; q < 4; ++q) acc[q] += wgt * (float)hv[q];
            }
        }
    }
#pragma unroll
    for (int q = 0; q < 4; ++q) {
        acc[q] += __shfl_xor(acc[q], 16);
        acc[q] += __shfl_xor(acc[q], 32);
    }
    dsum += __shfl_xor(dsum, 1); dsum += __shfl_xor(dsum, 2); dsum += __shfl_xor(dsum, 4);
    dsum += __shfl_xor(dsum, 8); dsum += __shfl_xor(dsum, 16); dsum += __shfl_xor(dsum, 32);
    float inv = 1.f / (dsum + 1e-16f);
    if (l < 16) {
        float4 o;
        o.x = acc[0] * inv + bias[cg * 4 + 0];
        o.y = acc[1] * inv + bias[cg * 4 + 1];
        o.z = acc[2] * inv + bias[cg * 4 + 2];
        o.w = acc[3] * inv + bias[cg * 4 + 3];
        *(float4*)(out + (size_t)n * OUTC + cg * 4) = o;
    }
}

// ---------------- launcher ----------------

extern "C" void kernel_launch(void* const* d_in, const int* in_sizes, int n_in,
                              void* d_out, int out_size, void* d_ws, size_t ws_size,
                              hipStream_t stream) {
    const float* x    = (const float*)d_in[0];
    const int*   ei   = (const int*)d_in[1];
    const float* W1   = (const float*)d_in[2];
    const float* as1w = (const float*)d_in[3];
    const float* ad1w = (const float*)d_in[4];
    const float* b1   = (const float*)d_in[5];
    const float* W2   = (const float*)d_in[6];
    const float* as2w = (const float*)d_in[7];
    const float* ad2w = (const float*)d_in[8];
    const float* b2   = (const float*)d_in[9];
    float* out = (float*)d_out;

    int N = in_sizes[0] / 128;
    int E = in_sizes[1] / 2;
    int Etot = E + N;
    int nb = (N + 255) / 256;
    int MB = (N + 63) / 64;

    char* p = (char*)d_ws;
    auto alloc = [&](size_t bytes) { char* r = p; p += (bytes + 255) & ~(size_t)255; return r; };
    _Float16* h1  = (_Float16*)alloc((size_t)N * HH * 2);
    _Float16* o1h = (_Float16*)alloc((size_t)N * HH * 2);
    _Float16* h2  = (_Float16*)alloc((size_t)N * OUTC * 2);
    _Float16* W1t = (_Float16*)alloc((size_t)128 * HH * 2);
    _Float16* W2t = (_Float16*)alloc((size_t)HH * OUTC * 2);
    float* a_s1 = (float*)alloc((size_t)N * 8 * 4);
    float* a_d1 = (float*)alloc((size_t)N * 8 * 4);
    float* a_s2 = (float*)alloc((size_t)N * 4);
    float* a_d2 = (float*)alloc((size_t)N * 4);
    int* deg    = (int*)  alloc((size_t)N * 4);
    int* offs   = (int*)  alloc((size_t)(N + 1) * 4);
    int* cursor = (int*)  alloc((size_t)N * 4);
    int* part   = (int*)  alloc((size_t)nb * 4);
    int* esrc   = (int*)  alloc((size_t)Etot * 4);

    // CSR by destination (includes self-loops)
    hipMemsetAsync(deg, 0, sizeof(int) * N, stream);
    hist_kernel<<<(Etot + 255) / 256, 256, 0, stream>>>(ei, E, N, deg);
    scan_block<<<nb, 256, 0, stream>>>(deg, offs, part, N);
    scan_part<<<1, 256, 0, stream>>>(part, nb);
    scan_add<<<nb, 256, 0, stream>>>(offs, part, N);
    hipMemcpyAsync(cursor, offs, sizeof(int) * N, hipMemcpyDeviceToDevice, stream);
    scatter_kernel<<<(Etot + 255) / 256, 256, 0, stream>>>(ei, E, N, cursor, esrc);

    // weight transpose+cast (tiny)
    cast_wt<<<(128 * HH + 255) / 256, 256, 0, stream>>>(W1, W1t, 128, HH);
    cast_wt<<<(HH * OUTC + 255) / 256, 256, 0, stream>>>(W2, W2t, HH, OUTC);

    // layer 1: MFMA GEMM -> scores -> aggregate (bias+ReLU fused, fp16 out)
    mfma_gemm<128, 16, true><<<MB, 256, 0, stream>>>(x, W1t, h1, N);
    att1_kernel<<<N, 64, 0, stream>>>(h1, as1w, ad1w, a_s1, a_d1);
    agg1_kernel<<<N / 4, 256, 0, stream>>>(offs, esrc, a_s1, a_d1, h1, b1, o1h);

    // layer 2
    mfma_gemm<256, 4, false><<<MB, 256, 0, stream>>>(o1h, W2t, h2, N);
    att2_kernel<<<N, 64, 0, stream>>>(h2, as2w, ad2w, a_s2, a_d2);
    agg2_kernel<<<N / 4, 256, 0, stream>>>(offs, esrc, a_s2, a_d2, h2, b2, out);
}

// Round 6
// 275.050 us; speedup vs baseline: 1.6940x; 1.0545x over previous
//
#include <hip/hip_runtime.h>
#include <cstddef>

#define HH   256   // HEADS*HID
#define OUTC 64
#define NEG  0.2f

typedef _Float16 half8  __attribute__((ext_vector_type(8)));
typedef _Float16 half4v __attribute__((ext_vector_type(4)));
typedef float    f32x4  __attribute__((ext_vector_type(4)));

// ---------------- CSR build ----------------

__global__ __launch_bounds__(256) void hist_kernel(const int* __restrict__ ei, int E, int N,
                                                   int* __restrict__ deg) {
    int i = blockIdx.x * blockDim.x + threadIdx.x;
    int tot = E + N;
    if (i >= tot) return;
    int dst = (i < E) ? ei[E + i] : (i - E);   // self-loop for i>=E
    atomicAdd(&deg[dst], 1);
}

__global__ __launch_bounds__(256) void scan_block(const int* __restrict__ deg,
                                                  int* __restrict__ offs,
                                                  int* __restrict__ part, int n) {
    __shared__ int sh[256];
    int t = threadIdx.x;
    int i = blockIdx.x * 256 + t;
    int v = (i < n) ? deg[i] : 0;
    sh[t] = v;
    __syncthreads();
    for (int off = 1; off < 256; off <<= 1) {
        int x = (t >= off) ? sh[t - off] : 0;
        __syncthreads();
        sh[t] += x;
        __syncthreads();
    }
    if (i < n) offs[i + 1] = sh[t];
    if (t == 255) part[blockIdx.x] = sh[255];
}

__global__ __launch_bounds__(256) void scan_part(int* __restrict__ part, int nb) {
    __shared__ int sh[256];
    int t = threadIdx.x;
    int v = (t < nb) ? part[t] : 0;
    sh[t] = v;
    __syncthreads();
    for (int off = 1; off < 256; off <<= 1) {
        int x = (t >= off) ? sh[t - off] : 0;
        __syncthreads();
        sh[t] += x;
        __syncthreads();
    }
    int excl = (t == 0) ? 0 : sh[t - 1];
    __syncthreads();
    if (t < nb) part[t] = excl;
}

// finalize offsets AND write scatter cursor (= segment start) in one pass
__global__ __launch_bounds__(256) void scan_add(int* __restrict__ offs,
                                                int* __restrict__ cursor,
                                                const int* __restrict__ deg,
                                                const int* __restrict__ part, int n) {
    int i = blockIdx.x * 256 + threadIdx.x;
    if (i < n) {
        int v = offs[i + 1] + part[blockIdx.x];
        offs[i + 1] = v;
        cursor[i] = v - deg[i];
    }
    if (i == 0) offs[0] = 0;
}

__global__ __launch_bounds__(256) void scatter_kernel(const int* __restrict__ ei, int E, int N,
                                                      int* __restrict__ cursor,
                                                      int* __restrict__ esrc) {
    int i = blockIdx.x * blockDim.x + threadIdx.x;
    int tot = E + N;
    if (i >= tot) return;
    int src, dst;
    if (i < E) { src = ei[i]; dst = ei[E + i]; }
    else       { src = dst = i - E; }
    int pos = atomicAdd(&cursor[dst], 1);
    esrc[pos] = src;
}

// ---------------- both weight transposes+casts in one dispatch ----------------
// W1t[n][k] = W1[k][n] (128x256 -> 256x128); W2t[n][k] = W2[k][n] (256x64 -> 64x256)

__global__ __launch_bounds__(256) void cast_both(const float* __restrict__ W1,
                                                 const float* __restrict__ W2,
                                                 _Float16* __restrict__ W1t,
                                                 _Float16* __restrict__ W2t) {
    int i = blockIdx.x * 256 + threadIdx.x;
    const int n1 = 128 * HH;
    if (i < n1) {
        int n = i / 128, k = i - n * 128;
        W1t[i] = (_Float16)W1[(size_t)k * HH + n];
    } else {
        int jj = i - n1;
        if (jj < HH * OUTC) {
            int n = jj / HH, k = jj - n * HH;
            W2t[jj] = (_Float16)W2[(size_t)k * OUTC + n];
        }
    }
}

// ---------------- MFMA fp16 GEMM, full-N per block, fused att-score epilogue ----------------
// C[M,N] = A[M,K] @ B[K,N], B given as Bt[N][K]. C stored fp16.
// as_[row*HEADS+h] = sum_c C[row][col]*atts[col] over cols of head h (atts flat [H*W]).

template <int K, int NT, int HEADS, bool AF32>
__global__ __launch_bounds__(256) void mfma_gemm(const void* __restrict__ Av,
                                                 const _Float16* __restrict__ Bt,
                                                 _Float16* __restrict__ C,
                                                 const float* __restrict__ atts,
                                                 const float* __restrict__ attd,
                                                 float* __restrict__ as_,
                                                 float* __restrict__ ad_,
                                                 int M) {
    constexpr int N = NT * 16;
    int t = threadIdx.x;
    int w = t >> 6, l = t & 63;
    int lm = l & 15, lk = l >> 4;
    int row0 = blockIdx.x * 64 + w * 16;
    int rA = row0 + lm; if (rA >= M) rA = M - 1;
    int kOff = lk * 8;

    f32x4 acc[NT];
#pragma unroll
    for (int i = 0; i < NT; ++i) acc[i] = (f32x4){0.f, 0.f, 0.f, 0.f};

    const float*    Af = (const float*)Av    + (size_t)rA * K + kOff;
    const _Float16* Ah = (const _Float16*)Av + (size_t)rA * K + kOff;
    const _Float16* Bp = Bt + (size_t)lm * K + kOff;

#pragma unroll 1
    for (int ks = 0; ks < K / 32; ++ks) {
        half8 a;
        if constexpr (AF32) {
            float4 a0 = *(const float4*)(Af + ks * 32);
            float4 a1 = *(const float4*)(Af + ks * 32 + 4);
            a = (half8){(_Float16)a0.x, (_Float16)a0.y, (_Float16)a0.z, (_Float16)a0.w,
                        (_Float16)a1.x, (_Float16)a1.y, (_Float16)a1.z, (_Float16)a1.w};
        } else {
            a = *(const half8*)(Ah + ks * 32);
        }
#pragma unroll
        for (int nt = 0; nt < NT; ++nt) {
            half8 b = *(const half8*)(Bp + (size_t)nt * 16 * K + ks * 32);
            acc[nt] = __builtin_amdgcn_mfma_f32_16x16x32_f16(a, b, acc[nt], 0, 0, 0);
        }
    }

    // store C fp16: row = rBase + r, col = nt*16 + lm
    int rBase = row0 + lk * 4;
#pragma unroll
    for (int nt = 0; nt < NT; ++nt) {
        int col = nt * 16 + lm;
#pragma unroll
        for (int r = 0; r < 4; ++r) {
            int row = rBase + r;
            if (row < M) C[(size_t)row * N + col] = (_Float16)acc[nt][r];
        }
    }

    // fused attention-score dots (all shfls unconditional & wave-uniform)
    float sv[NT], dv[NT];
#pragma unroll
    for (int nt = 0; nt < NT; ++nt) {
        sv[nt] = atts[nt * 16 + lm];
        dv[nt] = attd[nt * 16 + lm];
    }
    constexpr int TPH = NT / HEADS;
#pragma unroll
    for (int r = 0; r < 4; ++r) {
        int row = rBase + r;
#pragma unroll
        for (int hh = 0; hh < HEADS; ++hh) {
            float ps = 0.f, pd = 0.f;
#pragma unroll
            for (int q = 0; q < TPH; ++q) {
                int nt = hh * TPH + q;
                float v = acc[nt][r];
                ps += v * sv[nt];
                pd += v * dv[nt];
            }
            ps += __shfl_xor(ps, 1); ps += __shfl_xor(ps, 2);
            ps += __shfl_xor(ps, 4); ps += __shfl_xor(ps, 8);
            pd += __shfl_xor(pd, 1); pd += __shfl_xor(pd, 2);
            pd += __shfl_xor(pd, 4); pd += __shfl_xor(pd, 8);
            if (lm == 0 && row < M) {
                as_[(size_t)row * HEADS + hh] = ps;
                ad_[(size_t)row * HEADS + hh] = pd;
            }
        }
    }
}

// ---------------- layer-1 aggregation: software-pipelined scores ----------------
// writes o1h = fp16 ReLU(agg + bias). All shfls unconditional (r3/r4 lesson).

__global__ __launch_bounds__(256) void agg1_kernel(const int* __restrict__ offs,
                                                   const int* __restrict__ esrc,
                                                   const float* __restrict__ as_,
                                                   const float* __restrict__ ad_,
                                                   const _Float16* __restrict__ h,
                                                   const float* __restrict__ bias,
                                                   _Float16* __restrict__ o1h) {
    int n = blockIdx.x * 4 + (threadIdx.x >> 6);
    int l = threadIdx.x & 63;
    int beg = offs[n], deg = offs[n + 1] - beg;
    int hA = l & 7, j = l >> 3;     // score phase: slot j, head hA
    int cg = l & 31;                // channel group: channels cg*8..+7
    int hB = cg >> 2;               // head owning those channels
    int rs = l >> 5;                // row parity (even/odd slots)
    float adh = ad_[n * 8 + hA];

    // scores for chunk 0
    float ex_c = 0.f; int s_c = 0;
    if (j < deg) {
        s_c = esrc[beg + j];
        float e = as_[s_c * 8 + hA] + adh;
        e = (e > 0.f) ? e : NEG * e;
        ex_c = __expf(e);
    }

    float acc[8] = {0.f, 0.f, 0.f, 0.f, 0.f, 0.f, 0.f, 0.f};
    float dsum = 0.f;
    for (int cs = 0; cs < deg; cs += 8) {
        // prefetch next chunk's scores (hides esrc->as_ chain under h-gathers)
        float ex_n = 0.f; int s_n = 0;
        int inext = cs + 8 + j;
        if (inext < deg) {
            s_n = esrc[beg + inext];
            float e = as_[s_n * 8 + hA] + adh;
            e = (e > 0.f) ? e : NEG * e;
            ex_n = __expf(e);
        }
        dsum += ex_c;
        int lim = deg - cs;
        if (lim >= 8) {
#pragma unroll
            for (int it = 0; it < 4; ++it) {
                int slot = it * 2 + rs;
                int s2 = __shfl(s_c, slot * 8);
                float wgt = __shfl(ex_c, slot * 8 + hB);
                half8 hv = *(const half8*)(h + (size_t)s2 * HH + cg * 8);
#pragma unroll
                for (int q = 0; q < 8; ++q) acc[q] += wgt * (float)hv[q];
            }
        } else {
            int itmax = (lim + 1) >> 1;             // wave-uniform
            for (int it = 0; it < itmax; ++it) {
                int slot = it * 2 + rs;
                int s2 = __shfl(s_c, slot * 8);     // all lanes execute
                float wgt = __shfl(ex_c, slot * 8 + hB);
                if (slot < lim) {
                    half8 hv = *(const half8*)(h + (size_t)s2 * HH + cg * 8);
#pragma unroll
                    for (int q = 0; q < 8; ++q) acc[q] += wgt * (float)hv[q];
                }
            }
        }
        ex_c = ex_n; s_c = s_n;
    }
#pragma unroll
    for (int q = 0; q < 8; ++q) acc[q] += __shfl_xor(acc[q], 32);
    dsum += __shfl_xor(dsum, 8); dsum += __shfl_xor(dsum, 16); dsum += __shfl_xor(dsum, 32);
    float denom = __shfl(dsum, hB);
    float inv = 1.f / (denom + 1e-16f);
    if (l < 32) {
        half8 o;
#pragma unroll
        for (int q = 0; q < 8; ++q) {
            float v = acc[q] * inv + bias[cg * 8 + q];
            o[q] = (_Float16)fmaxf(v, 0.f);     // bias + ReLU fused, fp16 out
        }
        *(half8*)(o1h + (size_t)n * HH + cg * 8) = o;
    }
}

// ---------------- layer-2 aggregation: 1 head x 64ch, pipelined ----------------

__global__ __launch_bounds__(256) void agg2_kernel(const int* __restrict__ offs,
                                                   const int* __restrict__ esrc,
                                                   const float* __restrict__ as_,
                                                   const float* __restrict__ ad_,
                                                   const _Float16* __restrict__ h,
                                                   const float* __restrict__ bias,
                                                   float* __restrict__ out) {
    int n = blockIdx.x * 4 + (threadIdx.x >> 6);
    int l = threadIdx.x & 63;
    int beg = offs[n], deg = offs[n + 1] - beg;
    float adn = ad_[n];
    int cg = l & 15;                // channels cg*4..+3
    int rs = l >> 4;                // row slot 0..3

    float ex_c = 0.f; int s_c = 0;
    if (l < deg) {
        s_c = esrc[beg + l];
        float e = as_[s_c] + adn;
        e = (e > 0.f) ? e : NEG * e;
        ex_c = __expf(e);
    }

    float acc[4] = {0.f, 0.f, 0.f, 0.f};
    float dsum = 0.f;
    for (int cs = 0; cs < deg; cs += 64) {
        float ex_n = 0.f; int s_n = 0;
        int inext = cs + 64 + l;
        if (inext < deg) {
            s_n = esrc[beg + inext];
            float e = as_[s_n] + adn;
            e = (e > 0.f) ? e : NEG * e;
            ex_n = __expf(e);
        }
        dsum += ex_c;
        int lim = deg - cs; if (lim > 64) lim = 64;
        int gmax = (lim + 3) >> 2;                  // wave-uniform
        for (int g = 0; g < gmax; ++g) {
            int slot = g * 4 + rs;
            int s2 = __shfl(s_c, slot);             // all lanes execute
            float wgt = __shfl(ex_c, slot);
            if (slot < lim) {
                half4v hv = *(const half4v*)(h + (size_t)s2 * OUTC + cg * 4);
#pragma unroll
                for (int q = 0; q < 4; ++q) acc[q] += wgt * (float)hv[q];
            }
        }
        ex_c = ex_n; s_c = s_n;
    }
#pragma unroll
    for (int q = 0; q < 4; ++q) {
        acc[q] += __shfl_xor(acc[q], 16);
        acc[q] += __shfl_xor(acc[q], 32);
    }
    dsum += __shfl_xor(dsum, 1); dsum += __shfl_xor(dsum, 2); dsum += __shfl_xor(dsum, 4);
    dsum += __shfl_xor(dsum, 8); dsum += __shfl_xor(dsum, 16); dsum += __shfl_xor(dsum, 32);
    float inv = 1.f / (dsum + 1e-16f);
    if (l < 16) {
        float4 o;
        o.x = acc[0] * inv + bias[cg * 4 + 0];
        o.y = acc[1] * inv + bias[cg * 4 + 1];
        o.z = acc[2] * inv + bias[cg * 4 + 2];
        o.w = acc[3] * inv + bias[cg * 4 + 3];
        *(float4*)(out + (size_t)n * OUTC + cg * 4) = o;
    }
}

// ---------------- launcher ----------------

extern "C" void kernel_launch(void* const* d_in, const int* in_sizes, int n_in,
                              void* d_out, int out_size, void* d_ws, size_t ws_size,
                              hipStream_t stream) {
    const float* x    = (const float*)d_in[0];
    const int*   ei   = (const int*)d_in[1];
    const float* W1   = (const float*)d_in[2];
    const float* as1w = (const float*)d_in[3];
    const float* ad1w = (const float*)d_in[4];
    const float* b1   = (const float*)d_in[5];
    const float* W2   = (const float*)d_in[6];
    const float* as2w = (const float*)d_in[7];
    const float* ad2w = (const float*)d_in[8];
    const float* b2   = (const float*)d_in[9];
    float* out = (float*)d_out;

    int N = in_sizes[0] / 128;
    int E = in_sizes[1] / 2;
    int Etot = E + N;
    int nb = (N + 255) / 256;
    int MB = (N + 63) / 64;

    char* p = (char*)d_ws;
    auto alloc = [&](size_t bytes) { char* r = p; p += (bytes + 255) & ~(size_t)255; return r; };
    _Float16* h1  = (_Float16*)alloc((size_t)N * HH * 2);
    _Float16* o1h = (_Float16*)alloc((size_t)N * HH * 2);
    _Float16* h2  = (_Float16*)alloc((size_t)N * OUTC * 2);
    _Float16* W1t = (_Float16*)alloc((size_t)128 * HH * 2);
    _Float16* W2t = (_Float16*)alloc((size_t)HH * OUTC * 2);
    float* a_s1 = (float*)alloc((size_t)N * 8 * 4);
    float* a_d1 = (float*)alloc((size_t)N * 8 * 4);
    float* a_s2 = (float*)alloc((size_t)N * 4);
    float* a_d2 = (float*)alloc((size_t)N * 4);
    int* deg    = (int*)  alloc((size_t)N * 4);
    int* offs   = (int*)  alloc((size_t)(N + 1) * 4);
    int* cursor = (int*)  alloc((size_t)N * 4);
    int* part   = (int*)  alloc((size_t)nb * 4);
    int* esrc   = (int*)  alloc((size_t)Etot * 4);

    // CSR by destination (includes self-loops)
    hipMemsetAsync(deg, 0, sizeof(int) * N, stream);
    hist_kernel<<<(Etot + 255) / 256, 256, 0, stream>>>(ei, E, N, deg);
    scan_block<<<nb, 256, 0, stream>>>(deg, offs, part, N);
    scan_part<<<1, 256, 0, stream>>>(part, nb);
    scan_add<<<nb, 256, 0, stream>>>(offs, cursor, deg, part, N);
    scatter_kernel<<<(Etot + 255) / 256, 256, 0, stream>>>(ei, E, N, cursor, esrc);

    // weight transposes+casts (one dispatch)
    cast_both<<<(128 * HH + HH * OUTC + 255) / 256, 256, 0, stream>>>(W1, W2, W1t, W2t);

    // layer 1: MFMA GEMM (scores fused) -> aggregate (bias+ReLU fused, fp16 out)
    mfma_gemm<128, 16, 8, true><<<MB, 256, 0, stream>>>(x, W1t, h1, as1w, ad1w, a_s1, a_d1, N);
    agg1_kernel<<<N / 4, 256, 0, stream>>>(offs, esrc, a_s1, a_d1, h1, b1, o1h);

    // layer 2
    mfma_gemm<256, 4, 1, false><<<MB, 256, 0, stream>>>(o1h, W2t, h2, as2w, ad2w, a_s2, a_d2, N);
    agg2_kernel<<<N / 4, 256, 0, stream>>>(offs, esrc, a_s2, a_d2, h2, b2, out);
}